// Round 1
// baseline (206.600 us; speedup 1.0000x reference)
//
#include <hip/hip_runtime.h>
#include <hip/hip_bf16.h>

#define NROWS 8192
#define NC 256
#define KTOP 5
#define GAMMA 1.0f
#define MARGIN 2.0f
#define SPLITS 8
#define BM 64
#define TILES 16            // (NROWS/SPLITS)/BM = 1024/64
#define NSLOT (SPLITS * 2)  // per-row partial top5 slots (split x wn)

typedef __bf16 bf16x8 __attribute__((ext_vector_type(8)));
typedef float f32x4 __attribute__((ext_vector_type(4)));

static __device__ __forceinline__ void top5_insert(float (&t)[5], float v) {
    // t is sorted ascending; t[0] = current 5th-largest (threshold)
    if (v > t[0]) {
        t[0] = v;
#pragma unroll
        for (int j = 0; j < 4; ++j) {
            float lo = fminf(t[j], t[j + 1]);
            float hi = fmaxf(t[j], t[j + 1]);
            t[j] = lo;
            t[j + 1] = hi;
        }
    }
}

// ---------------- Kernel A: row-normalize fp32 -> bf16 ----------------
__global__ __launch_bounds__(256) void norm_cast_kernel(
    const float* __restrict__ a, const float* __restrict__ b,
    unsigned short* __restrict__ an, unsigned short* __restrict__ bn) {
    const float* src = blockIdx.y ? b : a;
    unsigned short* dst = blockIdx.y ? bn : an;
    int row = blockIdx.x * 4 + (threadIdx.x >> 6);
    int lane = threadIdx.x & 63;
    float4 v = reinterpret_cast<const float4*>(src + (size_t)row * NC)[lane];
    float ss = v.x * v.x + v.y * v.y + v.z * v.z + v.w * v.w;
#pragma unroll
    for (int off = 32; off >= 1; off >>= 1) ss += __shfl_xor(ss, off);
    float inv = rsqrtf(ss);
    __hip_bfloat16 h0 = __float2bfloat16(v.x * inv);
    __hip_bfloat16 h1 = __float2bfloat16(v.y * inv);
    __hip_bfloat16 h2 = __float2bfloat16(v.z * inv);
    __hip_bfloat16 h3 = __float2bfloat16(v.w * inv);
    ushort4 o;
    o.x = __builtin_bit_cast(unsigned short, h0);
    o.y = __builtin_bit_cast(unsigned short, h1);
    o.z = __builtin_bit_cast(unsigned short, h2);
    o.w = __builtin_bit_cast(unsigned short, h3);
    reinterpret_cast<ushort4*>(dst + (size_t)row * NC)[lane] = o;
}

// ------- Kernel B: fused sim GEMM + per-row running top-5 + diagonal -------
// grid = (NROWS/BM, SPLITS), block = 256 (4 waves, 2x2 over the 64x64 tile)
__global__ __launch_bounds__(256) void simtop_kernel(
    const unsigned short* __restrict__ predn,
    const unsigned short* __restrict__ targn,
    float* __restrict__ diag, float* __restrict__ top5p) {
    __shared__ float tbuf[4][32 * 33];  // per-wave 32x32 tile, row-major pad 33

    int tid = threadIdx.x, w = tid >> 6, lane = tid & 63;
    int wm = w >> 1, wn = w & 1;
    int bi = blockIdx.x, split = blockIdx.y;
    int wrbase = bi * BM + wm * 32;
    int l15 = lane & 15, lq = lane >> 4;

    // A fragments: 32 rows x K=256, held in registers (64 VGPR)
    bf16x8 afrag[2][8];
    const unsigned short* aptr = predn + (size_t)(wrbase + l15) * NC + lq * 8;
#pragma unroll
    for (int tm = 0; tm < 2; ++tm)
#pragma unroll
        for (int kk = 0; kk < 8; ++kk)
            afrag[tm][kk] =
                *reinterpret_cast<const bf16x8*>(aptr + tm * 16 * NC + kk * 32);

    float t5[5];
#pragma unroll
    for (int j = 0; j < 5; ++j) t5[j] = -1e30f;

    float* tb = tbuf[w];
    int srow = lane >> 1, shalf = lane & 1;  // scan: 2 lanes per row
    int grow = wrbase + srow;

    for (int t = 0; t < TILES; ++t) {
        int ctile = split * (TILES * BM) + t * BM;
        const unsigned short* bptr =
            targn + (size_t)(ctile + wn * 32 + l15) * NC + lq * 8;

        f32x4 zero = {0.f, 0.f, 0.f, 0.f};
        f32x4 acc[2][2];
#pragma unroll
        for (int i = 0; i < 2; ++i)
#pragma unroll
            for (int j = 0; j < 2; ++j) acc[i][j] = zero;

#pragma unroll
        for (int kk = 0; kk < 8; ++kk) {
            bf16x8 b0 = *reinterpret_cast<const bf16x8*>(bptr + kk * 32);
            bf16x8 b1 =
                *reinterpret_cast<const bf16x8*>(bptr + 16 * NC + kk * 32);
            acc[0][0] = __builtin_amdgcn_mfma_f32_16x16x32_bf16(
                afrag[0][kk], b0, acc[0][0], 0, 0, 0);
            acc[1][0] = __builtin_amdgcn_mfma_f32_16x16x32_bf16(
                afrag[1][kk], b0, acc[1][0], 0, 0, 0);
            acc[0][1] = __builtin_amdgcn_mfma_f32_16x16x32_bf16(
                afrag[0][kk], b1, acc[0][1], 0, 0, 0);
            acc[1][1] = __builtin_amdgcn_mfma_f32_16x16x32_bf16(
                afrag[1][kk], b1, acc[1][1], 0, 0, 0);
        }

        // dump wave's 32x32 tile to its private LDS buffer (no barrier needed)
#pragma unroll
        for (int tm = 0; tm < 2; ++tm)
#pragma unroll
            for (int tn = 0; tn < 2; ++tn) {
                int colb = tn * 16 + l15;
                int rowb = tm * 16 + lq * 4;
#pragma unroll
                for (int j = 0; j < 4; ++j)
                    tb[(rowb + j) * 33 + colb] = acc[tm][tn][j];
            }

        // scan: lane handles (row srow, 16 cols at shalf*16)
        int gcol0 = ctile + wn * 32 + shalf * 16;
        const float* rp = tb + srow * 33 + shalf * 16;
#pragma unroll
        for (int c = 0; c < 16; ++c) {
            float v = rp[c];
            int gcol = gcol0 + c;
            if (gcol == grow) {
                diag[grow] = v;  // capture diagonal, exclude from top5
            } else {
                top5_insert(t5, v);
            }
        }
    }

    // merge the two lanes (col halves) of each row: snapshot partner first
    float pv[5];
#pragma unroll
    for (int j = 0; j < 5; ++j) pv[j] = __shfl_xor(t5[j], 1);
#pragma unroll
    for (int j = 0; j < 5; ++j) top5_insert(t5, pv[j]);

    if (shalf == 0) {
        float* o = top5p + ((size_t)grow * NSLOT + split * 2 + wn) * KTOP;
#pragma unroll
        for (int j = 0; j < 5; ++j) o[j] = t5[j];
    }
}

// ---------------- Kernel C: merge partials + loss reduction ----------------
__global__ __launch_bounds__(256) void finalize_kernel(
    const float* __restrict__ diag, const float* __restrict__ top5p,
    float* __restrict__ out) {
    int row = blockIdx.x * 256 + threadIdx.x;
    float t5[5];
#pragma unroll
    for (int j = 0; j < 5; ++j) t5[j] = -1e30f;
    const float* p = top5p + (size_t)row * NSLOT * KTOP;
    for (int s = 0; s < NSLOT * KTOP; ++s) top5_insert(t5, p[s]);
    float d = diag[row];
    float sum = 0.f;
#pragma unroll
    for (int j = 0; j < 5; ++j)
        sum += fmaxf(t5[j] - GAMMA * d + MARGIN, 0.f);
#pragma unroll
    for (int off = 32; off >= 1; off >>= 1) sum += __shfl_xor(sum, off);
    __shared__ float red[4];
    int wv = threadIdx.x >> 6;
    if ((threadIdx.x & 63) == 0) red[wv] = sum;
    __syncthreads();
    if (threadIdx.x == 0) {
        float tot = red[0] + red[1] + red[2] + red[3];
        atomicAdd(out, tot * (1.0f / ((float)NROWS * KTOP)));
    }
}

extern "C" void kernel_launch(void* const* d_in, const int* in_sizes, int n_in,
                              void* d_out, int out_size, void* d_ws,
                              size_t ws_size, hipStream_t stream) {
    (void)in_sizes; (void)n_in; (void)out_size; (void)ws_size;
    const float* input = (const float*)d_in[0];
    const float* target = (const float*)d_in[1];
    char* ws = (char*)d_ws;
    unsigned short* predn = (unsigned short*)ws;                       // 4 MB
    unsigned short* targn = (unsigned short*)(ws + (size_t)NROWS * NC * 2);
    float* diag = (float*)(ws + (size_t)NROWS * NC * 4);               // 32 KB
    float* top5p = (float*)(ws + (size_t)NROWS * NC * 4 + NROWS * 4);  // 2.6 MB
    float* out = (float*)d_out;

    hipMemsetAsync(d_out, 0, sizeof(float), stream);

    dim3 gA(NROWS / 4, 2);
    norm_cast_kernel<<<gA, 256, 0, stream>>>(input, target, predn, targn);

    dim3 gB(NROWS / BM, SPLITS);
    simtop_kernel<<<gB, 256, 0, stream>>>(predn, targn, diag, top5p);

    finalize_kernel<<<NROWS / 256, 256, 0, stream>>>(diag, top5p, out);
}

// Round 4
// 196.106 us; speedup vs baseline: 1.0535x; 1.0535x over previous
//
#include <hip/hip_runtime.h>
#include <hip/hip_bf16.h>

#define NROWS 8192
#define NC 256
#define KTOP 5
#define GAMMA 1.0f
#define MARGIN 2.0f
#define SPLITS 8
#define BM 64
#define TILES 16            // (NROWS/SPLITS)/BM
#define NSLOT (SPLITS * 2)  // per-row partial top5 slots (split x wm)

typedef __bf16 bf16x8 __attribute__((ext_vector_type(8)));
typedef float f32x4 __attribute__((ext_vector_type(4)));

// branchless sorted-ascending top-5 insert: 5 max + 4 min, no divergence
static __device__ __forceinline__ void ins5(float (&t)[KTOP], float v) {
    t[0] = fmaxf(t[0], fminf(v, t[1]));
    t[1] = fmaxf(t[1], fminf(v, t[2]));
    t[2] = fmaxf(t[2], fminf(v, t[3]));
    t[3] = fmaxf(t[3], fminf(v, t[4]));
    t[4] = fmaxf(t[4], v);
}

// ---------------- Kernel A: row-normalize fp32 -> bf16 ----------------
__global__ __launch_bounds__(256) void norm_cast_kernel(
    const float* __restrict__ a, const float* __restrict__ b,
    unsigned short* __restrict__ an, unsigned short* __restrict__ bn) {
    const float* src = blockIdx.y ? b : a;
    unsigned short* dst = blockIdx.y ? bn : an;
    int row = blockIdx.x * 4 + (threadIdx.x >> 6);
    int lane = threadIdx.x & 63;
    float4 v = reinterpret_cast<const float4*>(src + (size_t)row * NC)[lane];
    float ss = v.x * v.x + v.y * v.y + v.z * v.z + v.w * v.w;
#pragma unroll
    for (int off = 32; off >= 1; off >>= 1) ss += __shfl_xor(ss, off);
    float inv = rsqrtf(ss);
    __hip_bfloat16 h0 = __float2bfloat16(v.x * inv);
    __hip_bfloat16 h1 = __float2bfloat16(v.y * inv);
    __hip_bfloat16 h2 = __float2bfloat16(v.z * inv);
    __hip_bfloat16 h3 = __float2bfloat16(v.w * inv);
    ushort4 o;
    o.x = __builtin_bit_cast(unsigned short, h0);
    o.y = __builtin_bit_cast(unsigned short, h1);
    o.z = __builtin_bit_cast(unsigned short, h2);
    o.w = __builtin_bit_cast(unsigned short, h3);
    reinterpret_cast<ushort4*>(dst + (size_t)row * NC)[lane] = o;
}

// ---------------- Kernel B helpers ----------------
static __device__ __forceinline__ void pf8(bf16x8 (&dst)[8],
                                           const unsigned short* p) {
#pragma unroll
    for (int kk = 0; kk < 8; ++kk)
        dst[kk] = *reinterpret_cast<const bf16x8*>(p + kk * 32);
}

// one 16(targ)x32(pred) half-step per wave:
// 16 MFMAs (full K=256) + in-register top-5 inserts + rare diag capture
static __device__ __forceinline__ void half_step(
    const bf16x8 (&buf)[8], const bf16x8 (&pb)[2][8], float (&t5)[2][KTOP],
    int targ16, int p16, int l15, int lq, float* __restrict__ diag) {
    f32x4 acc0 = {0.f, 0.f, 0.f, 0.f};
    f32x4 acc1 = {0.f, 0.f, 0.f, 0.f};
#pragma unroll
    for (int kk = 0; kk < 8; ++kk) {
        acc0 = __builtin_amdgcn_mfma_f32_16x16x32_bf16(buf[kk], pb[0][kk],
                                                       acc0, 0, 0, 0);
        acc1 = __builtin_amdgcn_mfma_f32_16x16x32_bf16(buf[kk], pb[1][kk],
                                                       acc1, 0, 0, 0);
    }
    bool hd0 = (targ16 == p16);       // diag falls in tn=0 block
    bool hd1 = (targ16 == p16 + 16);  // diag falls in tn=1 block
    if (__builtin_expect(hd0 || hd1, 0)) {
#pragma unroll
        for (int j = 0; j < 4; ++j) {
            float v0 = acc0[j], v1 = acc1[j];
            bool isd = (l15 == lq * 4 + j);
            bool d0 = hd0 && isd, d1 = hd1 && isd;
            if (d0) diag[p16 + l15] = v0;
            if (d1) diag[p16 + 16 + l15] = v1;
            ins5(t5[0], d0 ? -1e30f : v0);
            ins5(t5[1], d1 ? -1e30f : v1);
        }
    } else {
#pragma unroll
        for (int j = 0; j < 4; ++j) {
            ins5(t5[0], acc0[j]);
            ins5(t5[1], acc1[j]);
        }
    }
}

// ------- Kernel B: fused sim GEMM + per-row running top-5 + diagonal -------
// grid = (NROWS/BM, SPLITS), block = 256 (4 waves: wm=targ-half, wn=pred-half)
// Swapped operands: D = targ_tile x pred_block^T -> lane owns 2 pred rows.
__global__ __launch_bounds__(256, 2) void simtop_kernel(
    const unsigned short* __restrict__ predn,
    const unsigned short* __restrict__ targn,
    float* __restrict__ diag, float* __restrict__ top5p) {
    int tid = threadIdx.x, w = tid >> 6, lane = tid & 63;
    int wm = w >> 1, wn = w & 1;
    int bi = blockIdx.x, split = blockIdx.y;
    int predbase = bi * BM;
    int l15 = lane & 15, lq = lane >> 4;

    // resident pred fragments (B operand), loop-invariant: 64 VGPR
    bf16x8 pb[2][8];
    const unsigned short* pp =
        predn + (size_t)(predbase + wn * 32 + l15) * NC + lq * 8;
#pragma unroll
    for (int tn = 0; tn < 2; ++tn)
#pragma unroll
        for (int kk = 0; kk < 8; ++kk)
            pb[tn][kk] =
                *reinterpret_cast<const bf16x8*>(pp + tn * 16 * NC + kk * 32);

    float t5[2][KTOP];
#pragma unroll
    for (int tn = 0; tn < 2; ++tn)
#pragma unroll
        for (int j = 0; j < KTOP; ++j) t5[tn][j] = -1e30f;

    int tb0 = split * (TILES * BM) + wm * 32;  // this wave's targ row base
    int p16 = predbase + wn * 32;              // this wave's pred row base
    const unsigned short* tbase = targn + (size_t)(tb0 + l15) * NC + lq * 8;

    // double-buffered targ fragments (A operand), 16-row half-steps
    bf16x8 aX[8], aY[8];
    pf8(aX, tbase);  // (t=0, tm=0)

    for (int t = 0; t < TILES; ++t) {
        // prefetch (t, tm=1) then compute (t, tm=0)
        pf8(aY, tbase + (size_t)(t * BM + 16) * NC);
        half_step(aX, pb, t5, tb0 + t * BM, p16, l15, lq, diag);
        // prefetch (t+1, tm=0) then compute (t, tm=1)
        if (t + 1 < TILES) pf8(aX, tbase + (size_t)((t + 1) * BM) * NC);
        half_step(aY, pb, t5, tb0 + t * BM + 16, p16, l15, lq, diag);
    }

    // merge the 4 lq-lanes holding the same pred rows (butterfly over lanes
    // ^16 and ^32), then lanes with lq==0 write the per-split partial top5
#pragma unroll
    for (int tn = 0; tn < 2; ++tn) {
        float pv[KTOP];
#pragma unroll
        for (int j = 0; j < KTOP; ++j) pv[j] = __shfl_xor(t5[tn][j], 16);
#pragma unroll
        for (int j = 0; j < KTOP; ++j) ins5(t5[tn], pv[j]);
#pragma unroll
        for (int j = 0; j < KTOP; ++j) pv[j] = __shfl_xor(t5[tn][j], 32);
#pragma unroll
        for (int j = 0; j < KTOP; ++j) ins5(t5[tn], pv[j]);
    }
    if (lq == 0) {
#pragma unroll
        for (int tn = 0; tn < 2; ++tn) {
            int grow = p16 + tn * 16 + l15;
            float* o = top5p + ((size_t)grow * NSLOT + split * 2 + wm) * KTOP;
#pragma unroll
            for (int j = 0; j < KTOP; ++j) o[j] = t5[tn][j];
        }
    }
}

// ---------------- Kernel C: merge partials + loss reduction ----------------
__global__ __launch_bounds__(256) void finalize_kernel(
    const float* __restrict__ diag, const float* __restrict__ top5p,
    float* __restrict__ out) {
    int row = blockIdx.x * 256 + threadIdx.x;
    float t5[KTOP];
#pragma unroll
    for (int j = 0; j < KTOP; ++j) t5[j] = -1e30f;
    const float* p = top5p + (size_t)row * NSLOT * KTOP;
    for (int s = 0; s < NSLOT * KTOP; ++s) ins5(t5, p[s]);
    float d = diag[row];
    float sum = 0.f;
#pragma unroll
    for (int j = 0; j < KTOP; ++j)
        sum += fmaxf(t5[j] - GAMMA * d + MARGIN, 0.f);
#pragma unroll
    for (int off = 32; off >= 1; off >>= 1) sum += __shfl_xor(sum, off);
    __shared__ float red[4];
    int wv = threadIdx.x >> 6;
    if ((threadIdx.x & 63) == 0) red[wv] = sum;
    __syncthreads();
    if (threadIdx.x == 0) {
        float tot = red[0] + red[1] + red[2] + red[3];
        atomicAdd(out, tot * (1.0f / ((float)NROWS * KTOP)));
    }
}

extern "C" void kernel_launch(void* const* d_in, const int* in_sizes, int n_in,
                              void* d_out, int out_size, void* d_ws,
                              size_t ws_size, hipStream_t stream) {
    (void)in_sizes; (void)n_in; (void)out_size; (void)ws_size;
    const float* input = (const float*)d_in[0];
    const float* target = (const float*)d_in[1];
    char* ws = (char*)d_ws;
    unsigned short* predn = (unsigned short*)ws;                       // 4 MB
    unsigned short* targn = (unsigned short*)(ws + (size_t)NROWS * NC * 2);
    float* diag = (float*)(ws + (size_t)NROWS * NC * 4);               // 32 KB
    float* top5p = (float*)(ws + (size_t)NROWS * NC * 4 + NROWS * 4);  // 2.6 MB
    float* out = (float*)d_out;

    hipMemsetAsync(d_out, 0, sizeof(float), stream);

    dim3 gA(NROWS / 4, 2);
    norm_cast_kernel<<<gA, 256, 0, stream>>>(input, target, predn, targn);

    dim3 gB(NROWS / BM, SPLITS);
    simtop_kernel<<<gB, 256, 0, stream>>>(predn, targn, diag, top5p);

    finalize_kernel<<<NROWS / 256, 256, 0, stream>>>(diag, top5p, out);
}

// Round 6
// 145.603 us; speedup vs baseline: 1.4189x; 1.3469x over previous
//
#include <hip/hip_runtime.h>
#include <hip/hip_bf16.h>

#define NROWS 8192
#define NC 256
#define KTOP 5
#define GAMMA 1.0f
#define MARGIN 2.0f
#define SPLITS 16   // targ row splits (512 rows each)
#define PREDB 512   // pred rows per block (8 waves x 64)
#define TROWS 512   // targ rows per split
#define TSTEPS 32   // TROWS / 16
#define NSLOT SPLITS

typedef __bf16 bf16x8 __attribute__((ext_vector_type(8)));
typedef float f32x4 __attribute__((ext_vector_type(4)));
typedef _Float16 h2 __attribute__((ext_vector_type(2)));

// packed-f16 sorted-ascending top-5 insert: both halves independent streams
// (lowers to v_pk_max_f16 / v_pk_min_f16)
static __device__ __forceinline__ void ins5pk(h2 (&t)[KTOP], h2 v) {
    t[0] = __builtin_elementwise_max(t[0], __builtin_elementwise_min(v, t[1]));
    t[1] = __builtin_elementwise_max(t[1], __builtin_elementwise_min(v, t[2]));
    t[2] = __builtin_elementwise_max(t[2], __builtin_elementwise_min(v, t[3]));
    t[3] = __builtin_elementwise_max(t[3], __builtin_elementwise_min(v, t[4]));
    t[4] = __builtin_elementwise_max(t[4], v);
}

static __device__ __forceinline__ void ins5f(float (&t)[KTOP], float v) {
    t[0] = fmaxf(t[0], fminf(v, t[1]));
    t[1] = fmaxf(t[1], fminf(v, t[2]));
    t[2] = fmaxf(t[2], fminf(v, t[3]));
    t[3] = fmaxf(t[3], fminf(v, t[4]));
    t[4] = fmaxf(t[4], v);
}

// ---------------- Kernel A: row-normalize fp32 -> bf16 ----------------
__global__ __launch_bounds__(256) void norm_cast_kernel(
    const float* __restrict__ a, const float* __restrict__ b,
    unsigned short* __restrict__ an, unsigned short* __restrict__ bn) {
    const float* src = blockIdx.y ? b : a;
    unsigned short* dst = blockIdx.y ? bn : an;
    int row = blockIdx.x * 4 + (threadIdx.x >> 6);
    int lane = threadIdx.x & 63;
    float4 v = reinterpret_cast<const float4*>(src + (size_t)row * NC)[lane];
    float ss = v.x * v.x + v.y * v.y + v.z * v.z + v.w * v.w;
#pragma unroll
    for (int off = 32; off >= 1; off >>= 1) ss += __shfl_xor(ss, off);
    float inv = rsqrtf(ss);
    __hip_bfloat16 h0 = __float2bfloat16(v.x * inv);
    __hip_bfloat16 h1 = __float2bfloat16(v.y * inv);
    __hip_bfloat16 h2v = __float2bfloat16(v.z * inv);
    __hip_bfloat16 h3 = __float2bfloat16(v.w * inv);
    ushort4 o;
    o.x = __builtin_bit_cast(unsigned short, h0);
    o.y = __builtin_bit_cast(unsigned short, h1);
    o.z = __builtin_bit_cast(unsigned short, h2v);
    o.w = __builtin_bit_cast(unsigned short, h3);
    reinterpret_cast<ushort4*>(dst + (size_t)row * NC)[lane] = o;
}

// ---------------- Kernel B helpers ----------------
static __device__ __forceinline__ void pf8(bf16x8 (&dst)[8],
                                           const unsigned short* p) {
#pragma unroll
    for (int kk = 0; kk < 8; ++kk)
        dst[kk] = *reinterpret_cast<const bf16x8*>(p + kk * 32);
}

// ------- Kernel B: fused sim GEMM + per-row running top-5 + diagonal -------
// grid = 256 (1/CU), block = 512 (8 waves). Each block: 512 pred rows x one
// 512-row targ split. Each wave owns 64 pred cols (4 MFMA col-groups, pb
// resident in 128 VGPRs); all 8 waves scan the same 16-targ-row step (A-loads
// L1-shared). blockIdx decoded so each XCD gets 4 splits x 8 pred-blocks
// (3 MB < 4 MB per-XCD L2).
__global__ __launch_bounds__(512)
__attribute__((amdgpu_waves_per_eu(2, 2)))
void simtop_kernel(const unsigned short* __restrict__ predn,
                   const unsigned short* __restrict__ targn,
                   float* __restrict__ diag, float* __restrict__ top5p) {
    int tid = threadIdx.x, w = tid >> 6, lane = tid & 63;
    int l15 = lane & 15, lq = lane >> 4;
    int id = blockIdx.x;
    int xcd = id & 7, jj = id >> 3;
    int split = (jj & 3) + 4 * (xcd >> 1);  // 16 splits, 4 per XCD
    int bi = (jj >> 2) + 8 * (xcd & 1);     // 16 pred blocks, 8 per XCD
    int pbase = bi * PREDB + w * 64;        // this wave's 64 pred cols
    int tb0 = split * TROWS;                // this block's targ rows

    // resident pred fragments (B operand): 4 groups x 8 kk = 128 VGPR
    bf16x8 pb0[8], pb1[8], pb2[8], pb3[8];
    {
        const unsigned short* pp = predn + (size_t)(pbase + l15) * NC + lq * 8;
#pragma unroll
        for (int kk = 0; kk < 8; ++kk) {
            pb0[kk] = *reinterpret_cast<const bf16x8*>(pp + kk * 32);
            pb1[kk] = *reinterpret_cast<const bf16x8*>(pp + 16 * NC + kk * 32);
            pb2[kk] = *reinterpret_cast<const bf16x8*>(pp + 32 * NC + kk * 32);
            pb3[kk] = *reinterpret_cast<const bf16x8*>(pp + 48 * NC + kk * 32);
        }
    }

    h2 t01[KTOP], t23[KTOP];
    h2 NEG = {(_Float16)-65504.f, (_Float16)-65504.f};
#pragma unroll
    for (int j = 0; j < KTOP; ++j) {
        t01[j] = NEG;
        t23[j] = NEG;
    }

    const unsigned short* tbase = targn + (size_t)(tb0 + l15) * NC + lq * 8;
    bool dblk = (bi == split);  // this block sees the diagonal

    // one 16-targ-row step: 32 MFMAs (full K=256) + packed top-5 inserts
    auto step_fn = [&](const bf16x8(&a)[8], int t) {
        f32x4 z = {0.f, 0.f, 0.f, 0.f};
        f32x4 acc0 = z, acc1 = z, acc2 = z, acc3 = z;
#pragma unroll
        for (int kk = 0; kk < 8; ++kk) {
            acc0 = __builtin_amdgcn_mfma_f32_16x16x32_bf16(a[kk], pb0[kk],
                                                           acc0, 0, 0, 0);
            acc1 = __builtin_amdgcn_mfma_f32_16x16x32_bf16(a[kk], pb1[kk],
                                                           acc1, 0, 0, 0);
            acc2 = __builtin_amdgcn_mfma_f32_16x16x32_bf16(a[kk], pb2[kk],
                                                           acc2, 0, 0, 0);
            acc3 = __builtin_amdgcn_mfma_f32_16x16x32_bf16(a[kk], pb3[kk],
                                                           acc3, 0, 0, 0);
        }
        // diagonal: only in block bi==split, wave w==t>>2, group g==t&3
        if (__builtin_expect(dblk && (t >> 2) == w, 0)) {
            int g = t & 3;
            int r0 = tb0 + t * 16;
#pragma unroll
            for (int j = 0; j < 4; ++j) {
                bool isd = (l15 == lq * 4 + j);
                float* dp = diag + r0 + lq * 4 + j;
                if (g == 0) {
                    if (isd) *dp = acc0[j];
                    acc0[j] = isd ? -65504.f : acc0[j];
                } else if (g == 1) {
                    if (isd) *dp = acc1[j];
                    acc1[j] = isd ? -65504.f : acc1[j];
                } else if (g == 2) {
                    if (isd) *dp = acc2[j];
                    acc2[j] = isd ? -65504.f : acc2[j];
                } else {
                    if (isd) *dp = acc3[j];
                    acc3[j] = isd ? -65504.f : acc3[j];
                }
            }
        }
#pragma unroll
        for (int j = 0; j < 4; ++j) {
            h2 v01 = {(_Float16)acc0[j], (_Float16)acc1[j]};
            h2 v23 = {(_Float16)acc2[j], (_Float16)acc3[j]};
            ins5pk(t01, v01);
            ins5pk(t23, v23);
        }
    };

    // double-buffered A fragments (16 targ rows each), ping-pong named bufs
    bf16x8 aX[8], aY[8];
    pf8(aX, tbase);
    for (int t = 0; t < TSTEPS; t += 2) {
        pf8(aY, tbase + (size_t)((t + 1) * 16) * NC);
        step_fn(aX, t);
        if (t + 2 < TSTEPS) pf8(aX, tbase + (size_t)((t + 2) * 16) * NC);
        step_fn(aY, t + 1);
    }

    // merge the 4 lq-lanes (same pred cols) via butterfly ^16, ^32
    auto merge = [&](h2(&t)[KTOP], int m) {
        h2 pv[KTOP];
#pragma unroll
        for (int j = 0; j < KTOP; ++j) {
            int x = __shfl_xor(__builtin_bit_cast(int, t[j]), m);
            pv[j] = __builtin_bit_cast(h2, x);
        }
#pragma unroll
        for (int j = 0; j < KTOP; ++j) ins5pk(t, pv[j]);
    };
    merge(t01, 16);
    merge(t01, 32);
    merge(t23, 16);
    merge(t23, 32);

    if (lq == 0) {
        // transposed partials [slot][j][row] for coalesced finalize reads
#pragma unroll
        for (int j = 0; j < KTOP; ++j) {
            float* base = top5p + (size_t)(split * KTOP + j) * NROWS + pbase;
            base[l15] = (float)t01[j].x;
            base[16 + l15] = (float)t01[j].y;
            base[32 + l15] = (float)t23[j].x;
            base[48 + l15] = (float)t23[j].y;
        }
    }
}

// ---------------- Kernel C: merge partials + loss reduction ----------------
__global__ __launch_bounds__(256) void finalize_kernel(
    const float* __restrict__ diag, const float* __restrict__ top5p,
    float* __restrict__ out) {
    int row = blockIdx.x * 256 + threadIdx.x;
    float t5[KTOP];
#pragma unroll
    for (int j = 0; j < KTOP; ++j) t5[j] = -1e30f;
    for (int sj = 0; sj < NSLOT * KTOP; ++sj)
        ins5f(t5, top5p[(size_t)sj * NROWS + row]);
    float d = diag[row];
    float sum = 0.f;
#pragma unroll
    for (int j = 0; j < KTOP; ++j)
        sum += fmaxf(t5[j] - GAMMA * d + MARGIN, 0.f);
#pragma unroll
    for (int off = 32; off >= 1; off >>= 1) sum += __shfl_xor(sum, off);
    __shared__ float red[4];
    int wv = threadIdx.x >> 6;
    if ((threadIdx.x & 63) == 0) red[wv] = sum;
    __syncthreads();
    if (threadIdx.x == 0) {
        float tot = red[0] + red[1] + red[2] + red[3];
        atomicAdd(out, tot * (1.0f / ((float)NROWS * KTOP)));
    }
}

extern "C" void kernel_launch(void* const* d_in, const int* in_sizes, int n_in,
                              void* d_out, int out_size, void* d_ws,
                              size_t ws_size, hipStream_t stream) {
    (void)in_sizes; (void)n_in; (void)out_size; (void)ws_size;
    const float* input = (const float*)d_in[0];
    const float* target = (const float*)d_in[1];
    char* ws = (char*)d_ws;
    unsigned short* predn = (unsigned short*)ws;                       // 4 MB
    unsigned short* targn = (unsigned short*)(ws + (size_t)NROWS * NC * 2);
    float* diag = (float*)(ws + (size_t)NROWS * NC * 4);               // 32 KB
    float* top5p = (float*)(ws + (size_t)NROWS * NC * 4 + NROWS * 4);  // 2.6 MB
    float* out = (float*)d_out;

    (void)hipMemsetAsync(d_out, 0, sizeof(float), stream);

    dim3 gA(NROWS / 4, 2);
    norm_cast_kernel<<<gA, 256, 0, stream>>>(input, target, predn, targn);

    simtop_kernel<<<256, 512, 0, stream>>>(predn, targn, diag, top5p);

    finalize_kernel<<<NROWS / 256, 256, 0, stream>>>(diag, top5p, out);
}

// Round 8
// 143.424 us; speedup vs baseline: 1.4405x; 1.0152x over previous
//
#include <hip/hip_runtime.h>
#include <hip/hip_bf16.h>

#define NROWS 8192
#define NC 256
#define KTOP 5
#define GAMMA 1.0f
#define MARGIN 2.0f
#define SPLITS 16   // targ row splits (512 rows each)
#define PREDB 512   // pred rows per block (8 waves x 64)
#define TROWS 512   // targ rows per split
#define TSTEPS 32   // TROWS / 16
#define NSLOT SPLITS

typedef __bf16 bf16x8 __attribute__((ext_vector_type(8)));
typedef float f32x4 __attribute__((ext_vector_type(4)));
typedef _Float16 h2 __attribute__((ext_vector_type(2)));

// packed-f16 sorted-ascending top-5 insert (v_pk_max_f16 / v_pk_min_f16)
static __device__ __forceinline__ void ins5pk(h2 (&t)[KTOP], h2 v) {
    t[0] = __builtin_elementwise_max(t[0], __builtin_elementwise_min(v, t[1]));
    t[1] = __builtin_elementwise_max(t[1], __builtin_elementwise_min(v, t[2]));
    t[2] = __builtin_elementwise_max(t[2], __builtin_elementwise_min(v, t[3]));
    t[3] = __builtin_elementwise_max(t[3], __builtin_elementwise_min(v, t[4]));
    t[4] = __builtin_elementwise_max(t[4], v);
}

static __device__ __forceinline__ void ins5f(float (&t)[KTOP], float v) {
    t[0] = fmaxf(t[0], fminf(v, t[1]));
    t[1] = fmaxf(t[1], fminf(v, t[2]));
    t[2] = fmaxf(t[2], fminf(v, t[3]));
    t[3] = fmaxf(t[3], fminf(v, t[4]));
    t[4] = fmaxf(t[4], v);
}

// f32 pair -> packed f16 (v_cvt_pkrtz_f16_f32), RTZ rounding is fine here
static __device__ __forceinline__ h2 pkrtz(float a, float b) {
    return __builtin_bit_cast(h2, __builtin_amdgcn_cvt_pkrtz(a, b));
}

// ---------------- Kernel A: row-normalize fp32 -> bf16 ----------------
__global__ __launch_bounds__(256) void norm_cast_kernel(
    const float* __restrict__ a, const float* __restrict__ b,
    unsigned short* __restrict__ an, unsigned short* __restrict__ bn) {
    const float* src = blockIdx.y ? b : a;
    unsigned short* dst = blockIdx.y ? bn : an;
    int row = blockIdx.x * 4 + (threadIdx.x >> 6);
    int lane = threadIdx.x & 63;
    float4 v = reinterpret_cast<const float4*>(src + (size_t)row * NC)[lane];
    float ss = v.x * v.x + v.y * v.y + v.z * v.z + v.w * v.w;
#pragma unroll
    for (int off = 32; off >= 1; off >>= 1) ss += __shfl_xor(ss, off);
    float inv = rsqrtf(ss);
    __hip_bfloat16 h0 = __float2bfloat16(v.x * inv);
    __hip_bfloat16 h1 = __float2bfloat16(v.y * inv);
    __hip_bfloat16 h2v = __float2bfloat16(v.z * inv);
    __hip_bfloat16 h3 = __float2bfloat16(v.w * inv);
    ushort4 o;
    o.x = __builtin_bit_cast(unsigned short, h0);
    o.y = __builtin_bit_cast(unsigned short, h1);
    o.z = __builtin_bit_cast(unsigned short, h2v);
    o.w = __builtin_bit_cast(unsigned short, h3);
    reinterpret_cast<ushort4*>(dst + (size_t)row * NC)[lane] = o;
}

// ---------------- Kernel B helpers ----------------
static __device__ __forceinline__ void pf8(bf16x8 (&dst)[8],
                                           const unsigned short* p) {
#pragma unroll
    for (int kk = 0; kk < 8; ++kk)
        dst[kk] = *reinterpret_cast<const bf16x8*>(p + kk * 32);
}

// ------- Kernel B: fused sim GEMM + per-row running top-5 + diagonal -------
// grid = 256 (1/CU), block = 512 (8 waves). Each block: 512 pred rows x one
// 512-row targ split; each wave owns 64 pred cols held RESIDENT in 128 VGPRs
// (asm-pinned so the compiler cannot sink the loads back into the loop).
__global__ __launch_bounds__(512)
__attribute__((amdgpu_waves_per_eu(2, 2)))
void simtop_kernel(const unsigned short* __restrict__ predn,
                   const unsigned short* __restrict__ targn,
                   float* __restrict__ diag, float* __restrict__ top5p) {
    int tid = threadIdx.x, w = tid >> 6, lane = tid & 63;
    int l15 = lane & 15, lq = lane >> 4;
    int id = blockIdx.x;
    int xcd = id & 7, jj = id >> 3;
    int split = (jj & 3) + 4 * (xcd >> 1);  // 16 splits, 4 per XCD
    int bi = (jj >> 2) + 8 * (xcd & 1);     // 16 pred blocks, 8 per XCD
    int pbase = bi * PREDB + w * 64;        // this wave's 64 pred cols
    int tb0 = split * TROWS;                // this block's targ rows

    // resident pred fragments (B operand): 4 groups x 8 kk = 128 VGPR.
    // Stored as f32x4, bit-cast to bf16x8 at MFMA use (free).
    f32x4 pb0[8], pb1[8], pb2[8], pb3[8];
    {
        const unsigned short* pp = predn + (size_t)(pbase + l15) * NC + lq * 8;
#pragma unroll
        for (int kk = 0; kk < 8; ++kk) {
            pb0[kk] = *reinterpret_cast<const f32x4*>(pp + kk * 32);
            pb1[kk] = *reinterpret_cast<const f32x4*>(pp + 16 * NC + kk * 32);
            pb2[kk] = *reinterpret_cast<const f32x4*>(pp + 32 * NC + kk * 32);
            pb3[kk] = *reinterpret_cast<const f32x4*>(pp + 48 * NC + kk * 32);
        }
    }
    // Opaque write: compiler may no longer rematerialize these from memory,
    // forcing true register residency for the whole K-loop.
#pragma unroll
    for (int kk = 0; kk < 8; ++kk)
        asm volatile("" : "+v"(pb0[kk]), "+v"(pb1[kk]), "+v"(pb2[kk]),
                          "+v"(pb3[kk]));

    h2 t01[KTOP], t23[KTOP];
    h2 NEG = {(_Float16)-65504.f, (_Float16)-65504.f};
#pragma unroll
    for (int j = 0; j < KTOP; ++j) {
        t01[j] = NEG;
        t23[j] = NEG;
    }

    const unsigned short* tbase = targn + (size_t)(tb0 + l15) * NC + lq * 8;
    bool dblk = (bi == split);  // this block sees the diagonal

    // one 16-targ-row step: 32 MFMAs (full K=256) + packed top-5 inserts
    auto step_fn = [&](const bf16x8(&a)[8], int t) {
        f32x4 z = {0.f, 0.f, 0.f, 0.f};
        f32x4 acc0 = z, acc1 = z, acc2 = z, acc3 = z;
#pragma unroll
        for (int kk = 0; kk < 8; ++kk) {
            acc0 = __builtin_amdgcn_mfma_f32_16x16x32_bf16(
                a[kk], __builtin_bit_cast(bf16x8, pb0[kk]), acc0, 0, 0, 0);
            acc1 = __builtin_amdgcn_mfma_f32_16x16x32_bf16(
                a[kk], __builtin_bit_cast(bf16x8, pb1[kk]), acc1, 0, 0, 0);
            acc2 = __builtin_amdgcn_mfma_f32_16x16x32_bf16(
                a[kk], __builtin_bit_cast(bf16x8, pb2[kk]), acc2, 0, 0, 0);
            acc3 = __builtin_amdgcn_mfma_f32_16x16x32_bf16(
                a[kk], __builtin_bit_cast(bf16x8, pb3[kk]), acc3, 0, 0, 0);
        }
        // diagonal: only in block bi==split, wave w==t>>2, group g==t&3
        if (__builtin_expect(dblk && (t >> 2) == w, 0)) {
            int g = t & 3;
            int r0 = tb0 + t * 16;
#pragma unroll
            for (int j = 0; j < 4; ++j) {
                bool isd = (l15 == lq * 4 + j);
                float* dp = diag + r0 + lq * 4 + j;
                if (g == 0) {
                    if (isd) *dp = acc0[j];
                    acc0[j] = isd ? -65504.f : acc0[j];
                } else if (g == 1) {
                    if (isd) *dp = acc1[j];
                    acc1[j] = isd ? -65504.f : acc1[j];
                } else if (g == 2) {
                    if (isd) *dp = acc2[j];
                    acc2[j] = isd ? -65504.f : acc2[j];
                } else {
                    if (isd) *dp = acc3[j];
                    acc3[j] = isd ? -65504.f : acc3[j];
                }
            }
        }
#pragma unroll
        for (int j = 0; j < 4; ++j) {
            ins5pk(t01, pkrtz(acc0[j], acc1[j]));
            ins5pk(t23, pkrtz(acc2[j], acc3[j]));
        }
    };

    // double-buffered A fragments (16 targ rows each), ping-pong named bufs
    bf16x8 aX[8], aY[8];
    pf8(aX, tbase);
    for (int t = 0; t < TSTEPS; t += 2) {
        pf8(aY, tbase + (size_t)((t + 1) * 16) * NC);
        step_fn(aX, t);
        if (t + 2 < TSTEPS) pf8(aX, tbase + (size_t)((t + 2) * 16) * NC);
        step_fn(aY, t + 1);
    }

    // merge the 4 lq-lanes (same pred cols) via butterfly ^16, ^32
    auto merge = [&](h2(&t)[KTOP], int m) {
        h2 pv[KTOP];
#pragma unroll
        for (int j = 0; j < KTOP; ++j) {
            int x = __shfl_xor(__builtin_bit_cast(int, t[j]), m);
            pv[j] = __builtin_bit_cast(h2, x);
        }
#pragma unroll
        for (int j = 0; j < KTOP; ++j) ins5pk(t, pv[j]);
    };
    merge(t01, 16);
    merge(t01, 32);
    merge(t23, 16);
    merge(t23, 32);

    if (lq == 0) {
        // transposed partials [slot][j][row] for coalesced finalize reads
#pragma unroll
        for (int j = 0; j < KTOP; ++j) {
            float* base = top5p + (size_t)(split * KTOP + j) * NROWS + pbase;
            base[l15] = (float)t01[j].x;
            base[16 + l15] = (float)t01[j].y;
            base[32 + l15] = (float)t23[j].x;
            base[48 + l15] = (float)t23[j].y;
        }
    }
}

// ---------------- Kernel C: merge partials + loss reduction ----------------
__global__ __launch_bounds__(256) void finalize_kernel(
    const float* __restrict__ diag, const float* __restrict__ top5p,
    float* __restrict__ out) {
    int row = blockIdx.x * 256 + threadIdx.x;
    float t5[KTOP];
#pragma unroll
    for (int j = 0; j < KTOP; ++j) t5[j] = -1e30f;
#pragma unroll 10
    for (int sj = 0; sj < NSLOT * KTOP; ++sj)
        ins5f(t5, top5p[(size_t)sj * NROWS + row]);
    float d = diag[row];
    float sum = 0.f;
#pragma unroll
    for (int j = 0; j < KTOP; ++j)
        sum += fmaxf(t5[j] - GAMMA * d + MARGIN, 0.f);
#pragma unroll
    for (int off = 32; off >= 1; off >>= 1) sum += __shfl_xor(sum, off);
    __shared__ float red[4];
    int wv = threadIdx.x >> 6;
    if ((threadIdx.x & 63) == 0) red[wv] = sum;
    __syncthreads();
    if (threadIdx.x == 0) {
        float tot = red[0] + red[1] + red[2] + red[3];
        atomicAdd(out, tot * (1.0f / ((float)NROWS * KTOP)));
    }
}

extern "C" void kernel_launch(void* const* d_in, const int* in_sizes, int n_in,
                              void* d_out, int out_size, void* d_ws,
                              size_t ws_size, hipStream_t stream) {
    (void)in_sizes; (void)n_in; (void)out_size; (void)ws_size;
    const float* input = (const float*)d_in[0];
    const float* target = (const float*)d_in[1];
    char* ws = (char*)d_ws;
    unsigned short* predn = (unsigned short*)ws;                       // 4 MB
    unsigned short* targn = (unsigned short*)(ws + (size_t)NROWS * NC * 2);
    float* diag = (float*)(ws + (size_t)NROWS * NC * 4);               // 32 KB
    float* top5p = (float*)(ws + (size_t)NROWS * NC * 4 + NROWS * 4);  // 2.6 MB
    float* out = (float*)d_out;

    (void)hipMemsetAsync(d_out, 0, sizeof(float), stream);

    dim3 gA(NROWS / 4, 2);
    norm_cast_kernel<<<gA, 256, 0, stream>>>(input, target, predn, targn);

    simtop_kernel<<<256, 512, 0, stream>>>(predn, targn, diag, top5p);

    finalize_kernel<<<NROWS / 256, 256, 0, stream>>>(diag, top5p, out);
}

// Round 9
// 114.061 us; speedup vs baseline: 1.8113x; 1.2574x over previous
//
#include <hip/hip_runtime.h>
#include <hip/hip_bf16.h>

#define NROWS 8192
#define NC 256
#define KTOP 5
#define GAMMA 1.0f
#define MARGIN 2.0f
#define NSPLIT 2     // targ splits (4096 rows each)
#define PREDB 64     // pred rows per block (2 pg x 32)
#define TCHUNK 128   // targ rows per LDS chunk
#define CHUNKS 32    // 4096 / 128
#define NSLOT NSPLIT

typedef __bf16 bf16x8 __attribute__((ext_vector_type(8)));
typedef float f32x4 __attribute__((ext_vector_type(4)));
typedef _Float16 h2 __attribute__((ext_vector_type(2)));

// packed-f16 sorted-ascending top-5 insert (v_pk_max_f16 / v_pk_min_f16)
static __device__ __forceinline__ void ins5pk(h2 (&t)[KTOP], h2 v) {
    t[0] = __builtin_elementwise_max(t[0], __builtin_elementwise_min(v, t[1]));
    t[1] = __builtin_elementwise_max(t[1], __builtin_elementwise_min(v, t[2]));
    t[2] = __builtin_elementwise_max(t[2], __builtin_elementwise_min(v, t[3]));
    t[3] = __builtin_elementwise_max(t[3], __builtin_elementwise_min(v, t[4]));
    t[4] = __builtin_elementwise_max(t[4], v);
}

static __device__ __forceinline__ void ins5f(float (&t)[KTOP], float v) {
    t[0] = fmaxf(t[0], fminf(v, t[1]));
    t[1] = fmaxf(t[1], fminf(v, t[2]));
    t[2] = fmaxf(t[2], fminf(v, t[3]));
    t[3] = fmaxf(t[3], fminf(v, t[4]));
    t[4] = fmaxf(t[4], v);
}

// f32 pair -> packed f16 (v_cvt_pkrtz_f16_f32)
static __device__ __forceinline__ h2 pkrtz(float a, float b) {
    return __builtin_bit_cast(h2, __builtin_amdgcn_cvt_pkrtz(a, b));
}

// ---------------- Kernel A: row-normalize fp32 -> bf16 ----------------
__global__ __launch_bounds__(256) void norm_cast_kernel(
    const float* __restrict__ a, const float* __restrict__ b,
    unsigned short* __restrict__ an, unsigned short* __restrict__ bn) {
    const float* src = blockIdx.y ? b : a;
    unsigned short* dst = blockIdx.y ? bn : an;
    int row = blockIdx.x * 4 + (threadIdx.x >> 6);
    int lane = threadIdx.x & 63;
    float4 v = reinterpret_cast<const float4*>(src + (size_t)row * NC)[lane];
    float ss = v.x * v.x + v.y * v.y + v.z * v.z + v.w * v.w;
#pragma unroll
    for (int off = 32; off >= 1; off >>= 1) ss += __shfl_xor(ss, off);
    float inv = rsqrtf(ss);
    __hip_bfloat16 h0 = __float2bfloat16(v.x * inv);
    __hip_bfloat16 h1 = __float2bfloat16(v.y * inv);
    __hip_bfloat16 h2v = __float2bfloat16(v.z * inv);
    __hip_bfloat16 h3 = __float2bfloat16(v.w * inv);
    ushort4 o;
    o.x = __builtin_bit_cast(unsigned short, h0);
    o.y = __builtin_bit_cast(unsigned short, h1);
    o.z = __builtin_bit_cast(unsigned short, h2v);
    o.w = __builtin_bit_cast(unsigned short, h3);
    reinterpret_cast<ushort4*>(dst + (size_t)row * NC)[lane] = o;
}

// ------- Kernel B: fused sim GEMM + per-row running top-5 + diagonal -------
// grid = 256 (1/CU): 128 pred-blocks x 2 targ-splits. Block = 512 thr =
// 8 waves (2 pred-groups x 4 targ-groups). Per wave: 32 pred rows resident
// in 64 VGPRs (proven-feasible residency size). Targ streamed via 128 KB
// double-buffered LDS in 128-row chunks; XOR-swizzled k-blocks kill bank
// conflicts; T14 issue-early/write-late staging hides L2 latency.
__global__ __launch_bounds__(512, 2) void simtop_kernel(
    const unsigned short* __restrict__ predn,
    const unsigned short* __restrict__ targn,
    float* __restrict__ diag, float* __restrict__ top5p) {
    __shared__ unsigned short tb[2][TCHUNK][NC];  // 2 x 64 KB

    int tid = threadIdx.x, w = tid >> 6, lane = tid & 63;
    int l15 = lane & 15, lq = lane >> 4;
    int bx = blockIdx.x;
    int split = bx & 1, bi = bx >> 1;
    int pg = w >> 2, tg = w & 3;
    int pgbase = bi * PREDB + pg * 32;  // wave's 32 pred cols
    int ts0 = split * (CHUNKS * TCHUNK);

    // resident pred fragments (B operand): 2 col-groups x 8 kk = 64 VGPR
    f32x4 pb0[8], pb1[8];
    {
        const unsigned short* pp = predn + (size_t)(pgbase + l15) * NC + lq * 8;
#pragma unroll
        for (int kk = 0; kk < 8; ++kk) {
            pb0[kk] = *reinterpret_cast<const f32x4*>(pp + kk * 32);
            pb1[kk] = *reinterpret_cast<const f32x4*>(pp + 16 * NC + kk * 32);
        }
    }
#pragma unroll
    for (int kk = 0; kk < 8; ++kk)
        asm volatile("" : "+v"(pb0[kk]), "+v"(pb1[kk]));

    h2 t01[KTOP];
    h2 NEG = {(_Float16)-65504.f, (_Float16)-65504.f};
#pragma unroll
    for (int j = 0; j < KTOP; ++j) t01[j] = NEG;

    // diagonal bookkeeping: which (chunk, tg) slice of this split sees it
    bool dblk = (split == (bi >> 6));
    int doffs = bi * PREDB + pg * 32 - ts0;  // valid only when dblk
    int cdiag = doffs >> 7;
    int tgdiag = (doffs >> 5) & 3;

    const char* tgbase = (const char*)(targn + (size_t)ts0 * NC);

    f32x4 sreg[8];  // per-thread 128B staging (T14 issue-early)
#define STAGE_LOAD(c)                                                       \
    {                                                                       \
        const char* src_ = tgbase + (size_t)(c) * (TCHUNK * NC * 2);        \
        _Pragma("unroll") for (int it = 0; it < 8; ++it) sreg[it] =         \
            *reinterpret_cast<const f32x4*>(src_ + it * 8192 + tid * 16);   \
    }
#define STAGE_STORE(pbuf)                                                   \
    {                                                                       \
        _Pragma("unroll") for (int it = 0; it < 8; ++it) {                  \
            int L_ = it * 8192 + tid * 16;                                  \
            int r_ = L_ >> 9, colb_ = L_ & 511;                             \
            int kb_ = colb_ >> 6, wo_ = colb_ & 63;                         \
            *reinterpret_cast<f32x4*>(                                      \
                &tb[pbuf][r_][((kb_ ^ (r_ & 7)) << 5) + (wo_ >> 1)]) =      \
                sreg[it];                                                   \
        }                                                                   \
    }

    STAGE_LOAD(0);
    STAGE_STORE(0);
    __syncthreads();

    int r0 = tg * 32 + l15, r1 = r0 + 16;  // wave's two targ row groups
    int sw0 = r0 & 7;                      // == r1 & 7

    for (int c = 0; c < CHUNKS; ++c) {
        int pbuf = c & 1;
        if (c + 1 < CHUNKS) STAGE_LOAD(c + 1);

        f32x4 z = {0.f, 0.f, 0.f, 0.f};
        f32x4 acc00 = z, acc01 = z, acc10 = z, acc11 = z;  // [cg][rg]
#pragma unroll
        for (int kk = 0; kk < 8; ++kk) {
            bf16x8 a0 = *reinterpret_cast<const bf16x8*>(
                &tb[pbuf][r0][((kk ^ sw0) << 5) + lq * 8]);
            bf16x8 a1 = *reinterpret_cast<const bf16x8*>(
                &tb[pbuf][r1][((kk ^ sw0) << 5) + lq * 8]);
            acc00 = __builtin_amdgcn_mfma_f32_16x16x32_bf16(
                a0, __builtin_bit_cast(bf16x8, pb0[kk]), acc00, 0, 0, 0);
            acc10 = __builtin_amdgcn_mfma_f32_16x16x32_bf16(
                a0, __builtin_bit_cast(bf16x8, pb1[kk]), acc10, 0, 0, 0);
            acc01 = __builtin_amdgcn_mfma_f32_16x16x32_bf16(
                a1, __builtin_bit_cast(bf16x8, pb0[kk]), acc01, 0, 0, 0);
            acc11 = __builtin_amdgcn_mfma_f32_16x16x32_bf16(
                a1, __builtin_bit_cast(bf16x8, pb1[kk]), acc11, 0, 0, 0);
        }

        int trowbase = ts0 + c * TCHUNK + tg * 32;
        if (__builtin_expect(dblk && c == cdiag && tg == tgdiag, 0)) {
            int pc0 = pgbase + l15, pc1 = pgbase + 16 + l15;
#pragma unroll
            for (int rg = 0; rg < 2; ++rg)
#pragma unroll
                for (int j = 0; j < 4; ++j) {
                    int tr = trowbase + rg * 16 + lq * 4 + j;
                    float v0 = (rg ? acc01 : acc00)[j];
                    float v1 = (rg ? acc11 : acc10)[j];
                    if (tr == pc0) { diag[pc0] = v0; v0 = -65504.f; }
                    if (tr == pc1) { diag[pc1] = v1; v1 = -65504.f; }
                    ins5pk(t01, pkrtz(v0, v1));
                }
        } else {
#pragma unroll
            for (int rg = 0; rg < 2; ++rg)
#pragma unroll
                for (int j = 0; j < 4; ++j) {
                    float v0 = (rg ? acc01 : acc00)[j];
                    float v1 = (rg ? acc11 : acc10)[j];
                    ins5pk(t01, pkrtz(v0, v1));
                }
        }

        if (c + 1 < CHUNKS) STAGE_STORE(pbuf ^ 1);
        __syncthreads();
    }

    // merge the 4 lq-lanes holding the same pred cols (butterfly ^16, ^32)
#pragma unroll
    for (int m = 16; m <= 32; m <<= 1) {
        h2 pv[KTOP];
#pragma unroll
        for (int j = 0; j < KTOP; ++j) {
            int x = __shfl_xor(__builtin_bit_cast(int, t01[j]), m);
            pv[j] = __builtin_bit_cast(h2, x);
        }
#pragma unroll
        for (int j = 0; j < KTOP; ++j) ins5pk(t01, pv[j]);
    }

    if (lq == 0) {
        // transposed partials [split][j][col] for coalesced finalize reads
#pragma unroll
        for (int j = 0; j < KTOP; ++j) {
            float* base = top5p + (size_t)(split * KTOP + j) * NROWS;
            base[pgbase + l15] = (float)t01[j].x;
            base[pgbase + 16 + l15] = (float)t01[j].y;
        }
    }
}

// ---------------- Kernel C: merge partials + loss reduction ----------------
__global__ __launch_bounds__(256) void finalize_kernel(
    const float* __restrict__ diag, const float* __restrict__ top5p,
    float* __restrict__ out) {
    int row = blockIdx.x * 256 + threadIdx.x;
    float t5[KTOP];
#pragma unroll
    for (int j = 0; j < KTOP; ++j) t5[j] = -1e30f;
#pragma unroll
    for (int sj = 0; sj < NSLOT * KTOP; ++sj)
        ins5f(t5, top5p[(size_t)sj * NROWS + row]);
    float d = diag[row];
    float sum = 0.f;
#pragma unroll
    for (int j = 0; j < KTOP; ++j)
        sum += fmaxf(t5[j] - GAMMA * d + MARGIN, 0.f);
#pragma unroll
    for (int off = 32; off >= 1; off >>= 1) sum += __shfl_xor(sum, off);
    __shared__ float red[4];
    int wv = threadIdx.x >> 6;
    if ((threadIdx.x & 63) == 0) red[wv] = sum;
    __syncthreads();
    if (threadIdx.x == 0) {
        float tot = red[0] + red[1] + red[2] + red[3];
        atomicAdd(out, tot * (1.0f / ((float)NROWS * KTOP)));
    }
}

extern "C" void kernel_launch(void* const* d_in, const int* in_sizes, int n_in,
                              void* d_out, int out_size, void* d_ws,
                              size_t ws_size, hipStream_t stream) {
    (void)in_sizes; (void)n_in; (void)out_size; (void)ws_size;
    const float* input = (const float*)d_in[0];
    const float* target = (const float*)d_in[1];
    char* ws = (char*)d_ws;
    unsigned short* predn = (unsigned short*)ws;                       // 4 MB
    unsigned short* targn = (unsigned short*)(ws + (size_t)NROWS * NC * 2);
    float* diag = (float*)(ws + (size_t)NROWS * NC * 4);               // 32 KB
    float* top5p = (float*)(ws + (size_t)NROWS * NC * 4 + NROWS * 4);  // 320 KB
    float* out = (float*)d_out;

    (void)hipMemsetAsync(d_out, 0, sizeof(float), stream);

    dim3 gA(NROWS / 4, 2);
    norm_cast_kernel<<<gA, 256, 0, stream>>>(input, target, predn, targn);

    simtop_kernel<<<256, 512, 0, stream>>>(predn, targn, diag, top5p);

    finalize_kernel<<<NROWS / 256, 256, 0, stream>>>(diag, top5p, out);
}